// Round 1
// baseline (65.747 us; speedup 1.0000x reference)
//
#include <hip/hip_runtime.h>
#include <hip/hip_bf16.h>
#include <stdint.h>

typedef __attribute__((ext_vector_type(8))) short bf16x8;
typedef __attribute__((ext_vector_type(4))) float f32x4;

#define MFMA16(a, b, c) __builtin_amdgcn_mfma_f32_16x16x32_bf16((a), (b), (c), 0, 0, 0)

__device__ __forceinline__ unsigned short f2bf(float f) {
    union { float f; uint32_t u; } v; v.f = f;
    return (unsigned short)((v.u + 0x7fffu + ((v.u >> 16) & 1u)) >> 16);
}

// ---------------------------------------------------------------------------
// prep_h: convert the 8 H tensors (8 blocks x 128 x 128 fp32 each) to bf16,
// transposed within each 128x128 block.
//   Wt[c][blk][i][j] = right_c[blk][j][i]   (stage-A B-operand, [N][K] layout)
//   Lt[c][blk][k][r] = left_c [blk][r][k]   (stage-B A-operand, [M][K] layout)
// 128 blocks: which(2) x c(8) x blk(8)
// ---------------------------------------------------------------------------
__global__ __launch_bounds__(256) void prep_h(
    const float* __restrict__ h2, const float* __restrict__ h3,
    const float* __restrict__ h4, const float* __restrict__ h5,
    const float* __restrict__ h6, const float* __restrict__ h7,
    const float* __restrict__ h8, const float* __restrict__ h9,
    unsigned short* __restrict__ wt, unsigned short* __restrict__ lt)
{
    // c-term tables: right = {hr1,hi1,hi2,hr2,hr3,hi3,hi4,hr4}
    //                left  = {hr1,hi1,hr2,hi2,hr3,hi3,hr4,hi4}
    const float* rmap[8] = {h2, h3, h5, h4, h6, h7, h9, h8};
    const float* lmap[8] = {h2, h3, h4, h5, h6, h7, h8, h9};
    const int wg = blockIdx.x;
    const int which = wg >> 6;       // 0 = Wt, 1 = Lt
    const int c = (wg >> 3) & 7;
    const int blk = wg & 7;
    const float* src = (which ? lmap[c] : rmap[c]) + blk * 16384;
    unsigned short* dst = (which ? lt : wt) + (c * 8 + blk) * 16384;

    __shared__ unsigned short tilebuf[128 * 129];
    const int t = threadIdx.x;
    #pragma unroll 4
    for (int i = 0; i < 64; ++i) {
        int idx = t + 256 * i;            // = r*128 + k, coalesced read
        int r = idx >> 7, k = idx & 127;
        tilebuf[r * 129 + k] = f2bf(src[idx]);
    }
    __syncthreads();
    #pragma unroll 4
    for (int i = 0; i < 64; ++i) {
        int idx = t + 256 * i;            // = k*128 + r, coalesced write
        int k = idx >> 7, r = idx & 127;
        dst[idx] = tilebuf[r * 129 + k];
    }
}

// ---------------------------------------------------------------------------
// prep_x: x (B,16,64,16,64,2) fp32 -> permuted bf16 planes Xre/Xim (B,1024,1024)
//   plane[b][row][col], row = p*128+si maps to src n1=perm[row>>6], r1=row&63
// Each thread handles 4 consecutive output cols (8 consecutive src floats).
// ---------------------------------------------------------------------------
__global__ __launch_bounds__(256) void prep_x(
    const float* __restrict__ x, const int* __restrict__ perm,
    unsigned short* __restrict__ xre, unsigned short* __restrict__ xim)
{
    const int id = blockIdx.x * 256 + threadIdx.x;   // 4*1024*256 total
    const int b = id >> 18;
    const int row = (id >> 8) & 1023;
    const int cg = id & 255;
    const int col0 = cg * 4;
    const int n1 = perm[row >> 6], r1 = row & 63;
    const int n2 = perm[col0 >> 6], r2 = col0 & 63;
    const int src = (((b * 16 + n1) * 64 + r1) * 16 + n2) * 64 + r2;  // float2 units
    const float4* s = (const float4*)(x + src * 2);
    float4 v0 = s[0], v1 = s[1];
    ushort4 re, im;
    re.x = f2bf(v0.x); re.y = f2bf(v0.z); re.z = f2bf(v1.x); re.w = f2bf(v1.z);
    im.x = f2bf(v0.y); im.y = f2bf(v0.w); im.z = f2bf(v1.y); im.w = f2bf(v1.w);
    const int o = id * 4;                 // = (b*1024+row)*1024 + col0
    *(ushort4*)(xre + o) = re;
    *(ushort4*)(xim + o) = im;
}

// ---------------------------------------------------------------------------
// bilin_main: one WG per (b,p,q). 4 waves in 2x2 grid, 64x64 tiles.
// Per c-term: stage A  U = X . W_c  (MFMA, X frags in regs, W direct from L2)
//             U^T -> LDS (bf16, [i][r] stride 136 -> 2-way banks = free)
//             stage B  Y(re|im) += Lt_c . U  (Lt direct from L2, U from LDS)
// c order groups by X-plane: {0,1,6,7} use Xre, {2,3,4,5} use Xim;
// within each group the first two c's accumulate Yre, the last two Yim.
// ---------------------------------------------------------------------------
__global__ __launch_bounds__(256, 1) void bilin_main(
    const unsigned short* __restrict__ xre,
    const unsigned short* __restrict__ xim,
    const unsigned short* __restrict__ wt,
    const unsigned short* __restrict__ lt,
    float* __restrict__ out)
{
    const int wg = blockIdx.x;
    const int q = wg & 7, p = (wg >> 3) & 7, b = wg >> 6;
    const int tid = threadIdx.x;
    const int lane = tid & 63, wid = tid >> 6;
    const int wm = wid >> 1, wn = wid & 1;
    const int lr = lane & 15, lg = lane >> 4;

    __shared__ __align__(16) unsigned short ulds[128 * 136];

    f32x4 yre[4][4], yim[4][4];
    #pragma unroll
    for (int i = 0; i < 4; ++i)
        #pragma unroll
        for (int j = 0; j < 4; ++j) {
            yre[i][j] = (f32x4){0.f, 0.f, 0.f, 0.f};
            yim[i][j] = (f32x4){0.f, 0.f, 0.f, 0.f};
        }

    #pragma unroll
    for (int g = 0; g < 2; ++g) {
        const unsigned short* xp = g ? xim : xre;
        const unsigned short* xbase =
            xp + (b * 1024 + p * 128 + wm * 64 + lr) * 1024 + q * 128 + lg * 8;
        bf16x8 xf[4][4];                          // 64 rows x 128 K, in regs
        #pragma unroll
        for (int mt = 0; mt < 4; ++mt)
            #pragma unroll
            for (int ks = 0; ks < 4; ++ks)
                xf[mt][ks] = *(const bf16x8*)(xbase + mt * 16384 + ks * 32);

        #pragma unroll
        for (int ci = 0; ci < 4; ++ci) {
            const int c = (g == 0) ? ((ci < 2) ? ci : ci + 4)      // 0,1,6,7
                                   : (ci + 2);                     // 2,3,4,5
            // ---- stage A: U = X . W_c
            const unsigned short* wbase =
                wt + (c * 8 + q) * 16384 + (wn * 64 + lr) * 128 + lg * 8;
            bf16x8 wf[4][4];
            #pragma unroll
            for (int nt = 0; nt < 4; ++nt)
                #pragma unroll
                for (int ks = 0; ks < 4; ++ks)
                    wf[nt][ks] = *(const bf16x8*)(wbase + nt * 2048 + ks * 32);
            f32x4 u[4][4];
            #pragma unroll
            for (int mt = 0; mt < 4; ++mt)
                #pragma unroll
                for (int nt = 0; nt < 4; ++nt)
                    u[mt][nt] = (f32x4){0.f, 0.f, 0.f, 0.f};
            #pragma unroll
            for (int ks = 0; ks < 4; ++ks)
                #pragma unroll
                for (int mt = 0; mt < 4; ++mt)
                    #pragma unroll
                    for (int nt = 0; nt < 4; ++nt)
                        u[mt][nt] = MFMA16(xf[mt][ks], wf[nt][ks], u[mt][nt]);

            // prefetch Lt frags (independent of LDS; overlaps write+barrier)
            const unsigned short* lbase =
                lt + (c * 8 + p) * 16384 + (wm * 64 + lr) * 128 + lg * 8;
            bf16x8 lf[4][4];
            #pragma unroll
            for (int mt = 0; mt < 4; ++mt)
                #pragma unroll
                for (int ks = 0; ks < 4; ++ks)
                    lf[mt][ks] = *(const bf16x8*)(lbase + mt * 2048 + ks * 32);

            // write U^T to LDS: [i][r] bf16, row stride 136 (banks 2-way, free)
            unsigned short* uw = ulds + (wn * 64 + lr) * 136 + wm * 64 + lg * 4;
            #pragma unroll
            for (int nt = 0; nt < 4; ++nt)
                #pragma unroll
                for (int mt = 0; mt < 4; ++mt) {
                    ushort4 hv;
                    hv.x = f2bf(u[mt][nt][0]);
                    hv.y = f2bf(u[mt][nt][1]);
                    hv.z = f2bf(u[mt][nt][2]);
                    hv.w = f2bf(u[mt][nt][3]);
                    *(ushort4*)(uw + nt * 2176 + mt * 16) = hv;
                }
            __syncthreads();

            // ---- stage B: Y += Lt_c . U
            const unsigned short* ubase = ulds + (wn * 64 + lr) * 136 + lg * 8;
            bf16x8 uf[4][4];
            #pragma unroll
            for (int nt = 0; nt < 4; ++nt)
                #pragma unroll
                for (int ks = 0; ks < 4; ++ks)
                    uf[nt][ks] = *(const bf16x8*)(ubase + nt * 2176 + ks * 32);
            #pragma unroll
            for (int ks = 0; ks < 4; ++ks)
                #pragma unroll
                for (int mt = 0; mt < 4; ++mt)
                    #pragma unroll
                    for (int nt = 0; nt < 4; ++nt) {
                        if (ci < 2)
                            yre[mt][nt] = MFMA16(lf[mt][ks], uf[nt][ks], yre[mt][nt]);
                        else
                            yim[mt][nt] = MFMA16(lf[mt][ks], uf[nt][ks], yim[mt][nt]);
                    }
            __syncthreads();
        }
    }

    // epilogue: interleave (re,im) -> coalesced float2 stores
    float2* o2 = (float2*)out;
    float2* obase = o2 + (b * 1024 + p * 128 + wm * 64 + lg * 4) * 1024
                       + q * 128 + wn * 64 + lr;
    #pragma unroll
    for (int mt = 0; mt < 4; ++mt)
        #pragma unroll
        for (int nt = 0; nt < 4; ++nt)
            #pragma unroll
            for (int j = 0; j < 4; ++j) {
                float2 v;
                v.x = yre[mt][nt][j];
                v.y = yim[mt][nt][j];
                obase[(mt * 16 + j) * 1024 + nt * 16] = v;
            }
}

extern "C" void kernel_launch(void* const* d_in, const int* in_sizes, int n_in,
                              void* d_out, int out_size, void* d_ws, size_t ws_size,
                              hipStream_t stream) {
    const float* x  = (const float*)d_in[0];
    const int* perm = (const int*)d_in[1];
    unsigned short* ws = (unsigned short*)d_ws;
    // workspace layout (ushort units): Xre 4M | Xim 4M | Wt 1M | Lt 1M = 20 MB
    unsigned short* xre = ws;
    unsigned short* xim = ws + 4u * 1024u * 1024u;
    unsigned short* wtp = ws + 8u * 1024u * 1024u;
    unsigned short* ltp = ws + 9u * 1024u * 1024u;

    hipLaunchKernelGGL(prep_h, dim3(128), dim3(256), 0, stream,
        (const float*)d_in[2], (const float*)d_in[3], (const float*)d_in[4],
        (const float*)d_in[5], (const float*)d_in[6], (const float*)d_in[7],
        (const float*)d_in[8], (const float*)d_in[9], wtp, ltp);
    hipLaunchKernelGGL(prep_x, dim3(4096), dim3(256), 0, stream,
        x, perm, xre, xim);
    hipLaunchKernelGGL(bilin_main, dim3(256), dim3(256), 0, stream,
        xre, xim, wtp, ltp, (float*)d_out);
}